// Round 7
// baseline (97.526 us; speedup 1.0000x reference)
//
#include <hip/hip_runtime.h>

// LogSparseAttention: B=2, L=2048, H=8, E=D=64, S=2048. fp32 in/out.
// Mask row r: r<22 -> causal prefix 0..r; r>=22 -> window {r-10..r} +
// taps {r-10-2^i, i=0..10, >=0}. <=22 active keys/row.
// R7: block = 1024 threads = 16 consecutive rows of one (b,h). The union of
// the 16 rows' keys is 7 DENSE intervals: near [l0-26, l0+15] (42 keys,
// window + taps i<=4 merged) + far taps i=5..10 ([l0-10-2^i, +15], 16 each)
// = 138 keys. Stage them bf16-packed [Kx64|Vx64] (256 B/key) into LDS with
// coalesced reads (fp32->bf16 inline; no prep kernel). Per-wave compute is
// the validated R6 path (4 groups x 16 lanes, 6 chunks, DPP-tree dot,
// chain-free two-phase softmax) with global loads replaced by ds_read_b128
// via a slot remap. 256B LDS row stride -> b128 reads are bank-uniform.

#define BB 2
#define LL 2048
#define HH 8
#define EE 64
#define SS 2048
#define TROWS 16
#define NSLOT 138   // 42 near + 6*16 far

__device__ __forceinline__ unsigned short bf16_rne(float f) {
    unsigned int u = __float_as_uint(f);
    unsigned int r = u + 0x7FFFu + ((u >> 16) & 1u);
    return (unsigned short)(r >> 16);
}

template<int CTRL>
__device__ __forceinline__ float dpp_add(float v) {
    int t = __builtin_amdgcn_mov_dpp(__float_as_int(v), CTRL, 0xF, 0xF, false);
    return v + __int_as_float(t);
}

__device__ __forceinline__ void unpack8(const uint4 kv, float* e) {
    e[0] = __int_as_float((int)(kv.x << 16));
    e[1] = __int_as_float((int)(kv.x & 0xFFFF0000u));
    e[2] = __int_as_float((int)(kv.y << 16));
    e[3] = __int_as_float((int)(kv.y & 0xFFFF0000u));
    e[4] = __int_as_float((int)(kv.z << 16));
    e[5] = __int_as_float((int)(kv.z & 0xFFFF0000u));
    e[6] = __int_as_float((int)(kv.w << 16));
    e[7] = __int_as_float((int)(kv.w & 0xFFFF0000u));
}

__global__ __launch_bounds__(1024, 4) void logsparse_attn_kernel(
    const float* __restrict__ Q,
    const float* __restrict__ K,
    const float* __restrict__ V,
    float* __restrict__ O)
{
    __shared__ unsigned short smem[NSLOT * 128];   // 35,328 B

    const int tid = threadIdx.x;
    // XCD swizzle: 2048 blocks -> XCD x gets contiguous logical range
    const int lb = ((blockIdx.x & 7) << 8) | (blockIdx.x >> 3);
    const int bh = lb >> 7;            // 0..15
    const int l0 = (lb & 127) << 4;    // first row of this block
    const int b  = bh >> 3;
    const int h  = bh & 7;

    // ---- stage 138 packed rows into LDS (dense global reads) ----
    const size_t bhbase = (size_t)b * SS * HH * EE + (size_t)h * EE;
    #pragma unroll
    for (int it = 0; it < 3; ++it) {
        const int j = it * 1024 + tid;           // 16B unit id, 2208 total
        if (j < NSLOT * 16) {
            const int r = j >> 4;                // LDS slot
            const int p = j & 15;                // 16B part within 256B row
            int s = (r < 42) ? (l0 - 26 + r)
                             : (l0 - 10 - (32 << ((r - 42) >> 4)) + ((r - 42) & 15));
            s = min(max(s, 0), SS - 1);          // clamped rows only read masked
            const float* src = ((p < 8) ? K : V) + bhbase
                             + (size_t)s * (HH * EE) + ((size_t)(p & 7) << 3);
            const float4 a = *(const float4*)src;
            const float4 c = *(const float4*)(src + 4);
            uint4 w;
            w.x = bf16_rne(a.x) | ((unsigned)bf16_rne(a.y) << 16);
            w.y = bf16_rne(a.z) | ((unsigned)bf16_rne(a.w) << 16);
            w.z = bf16_rne(c.x) | ((unsigned)bf16_rne(c.y) << 16);
            w.w = bf16_rne(c.z) | ((unsigned)bf16_rne(c.w) << 16);
            *(uint4*)(smem + r * 128 + p * 8) = w;
        }
    }
    __syncthreads();

    // ---- per-wave compute: wave wv owns row l = l0 + wv ----
    const int lane = tid & 63;
    const int wv   = tid >> 6;          // 0..15
    const int l    = l0 + wv;
    const int t    = lane & 15;         // 0..7: K lanes, 8..15: V lanes
    const int g    = lane >> 4;         // key group 0..3
    const int t8   = t & 7;

    const size_t qbase = ((size_t)b * LL + l) * HH * EE + (size_t)h * EE;
    float qr[8];
    {
        const float4 a  = *(const float4*)(Q + qbase + 8 * t8);
        const float4 b4 = *(const float4*)(Q + qbase + 8 * t8 + 4);
        qr[0] = a.x;  qr[1] = a.y;  qr[2] = a.z;  qr[3] = a.w;
        qr[4] = b4.x; qr[5] = b4.y; qr[6] = b4.z; qr[7] = b4.w;
    }

    // wave-uniform active-key bookkeeping
    int ntaps, nkeys, w0;
    if (l < 22) { ntaps = 0; nkeys = l + 1; w0 = 0; }
    else {
        w0 = l - 10;
        ntaps = 32 - __clz(w0);
        if (ntaps > 11) ntaps = 11;
        nkeys = ntaps + 11;
    }

    // phase 0: 6 LDS reads (4 keys each)
    uint4 kv[6];
    #pragma unroll
    for (int c = 0; c < 6; ++c) {
        const int n  = 4 * c + g;
        const int nc = (n < nkeys) ? n : (nkeys - 1);
        int slot;
        if (l < 22) slot = nc + 26 - l0;
        else if (nc < ntaps) {
            const int i = ntaps - 1 - nc;
            slot = (i <= 4) ? ((l - l0) + 16 - (1 << i))
                            : (42 + ((i - 5) << 4) + (l - l0));
        } else slot = (w0 + nc - ntaps) - l0 + 26;
        kv[c] = *(const uint4*)(smem + slot * 128 + t * 8);
    }

    // phase 1: dots (K lanes contribute, V lanes 0; DPP tree -> 16-lane sum)
    float sc[6];
    #pragma unroll
    for (int c = 0; c < 6; ++c) {
        float e[8];
        unpack8(kv[c], e);
        float p = qr[0]*e[0] + qr[1]*e[1] + qr[2]*e[2] + qr[3]*e[3]
                + qr[4]*e[4] + qr[5]*e[5] + qr[6]*e[6] + qr[7]*e[7];
        p = (t < 8) ? p : 0.0f;
        p = dpp_add<0xB1>(p);    // xor1
        p = dpp_add<0x4E>(p);    // xor2
        p = dpp_add<0x124>(p);   // row_ror:4
        p = dpp_add<0x128>(p);   // row_ror:8
        sc[c] = ((4 * c + g) < nkeys) ? p * 0.125f : -1e30f;
    }

    float mg = sc[0];
    #pragma unroll
    for (int c = 1; c < 6; ++c) mg = fmaxf(mg, sc[c]);

    // phase 2: weights + V accumulate
    float lsum = 0.0f;
    float acc[8] = {0.f,0.f,0.f,0.f,0.f,0.f,0.f,0.f};
    #pragma unroll
    for (int c = 0; c < 6; ++c) {
        const float w = __expf(sc[c] - mg);
        lsum += w;
        float e[8];
        unpack8(kv[c], e);
        #pragma unroll
        for (int j = 0; j < 8; ++j) acc[j] += w * e[j];
    }

    // global max + rescale; fully-invalid group annihilated by r=0
    float M = mg;
    M = fmaxf(M, __shfl_xor(M, 16, 64));
    M = fmaxf(M, __shfl_xor(M, 32, 64));
    const float r = __expf(mg - M);
    lsum *= r;
    #pragma unroll
    for (int j = 0; j < 8; ++j) acc[j] *= r;

    lsum += __shfl_xor(lsum, 16, 64);
    lsum += __shfl_xor(lsum, 32, 64);
    #pragma unroll
    for (int j = 0; j < 8; ++j) {
        acc[j] += __shfl_xor(acc[j], 16, 64);
        acc[j] += __shfl_xor(acc[j], 32, 64);
    }

    if (g == 0 && t >= 8) {
        const float inv = 1.0f / lsum;
        float4 o0, o1;
        o0.x = acc[0]*inv; o0.y = acc[1]*inv; o0.z = acc[2]*inv; o0.w = acc[3]*inv;
        o1.x = acc[4]*inv; o1.y = acc[5]*inv; o1.z = acc[6]*inv; o1.w = acc[7]*inv;
        *(float4*)(O + qbase + 8 * t8)     = o0;
        *(float4*)(O + qbase + 8 * t8 + 4) = o1;
    }
}

extern "C" void kernel_launch(void* const* d_in, const int* in_sizes, int n_in,
                              void* d_out, int out_size, void* d_ws, size_t ws_size,
                              hipStream_t stream) {
    const float* Q = (const float*)d_in[0];
    const float* K = (const float*)d_in[1];
    const float* V = (const float*)d_in[2];
    // d_in[3] = attention_mask (all-ones, unused by the reference math)
    float* O = (float*)d_out;

    const int blocks = (BB * HH * LL) / TROWS;   // 2048
    hipLaunchKernelGGL(logsparse_attn_kernel, dim3(blocks), dim3(1024), 0, stream,
                       Q, K, V, O);
}

// Round 9
// 95.968 us; speedup vs baseline: 1.0162x; 1.0162x over previous
//
#include <hip/hip_runtime.h>

// LogSparseAttention: B=2, L=2048, H=8, E=D=64, S=2048. fp32 in/out.
// Mask row r (from reference _row_mask, L==S==2048, log_l=11):
//   r < 22 : keys 0..r (full causal prefix)
//   r >= 22: window {r-10..r} + taps {r-10-2^i, i=0..10, >= 0}
// <=22 active keys/row -> 6 chunks of 4 keys. Wave = one (b,h,l) row,
// 4 groups x 16 lanes; group g owns key ordinal 4c+g, lane (g,t) dims 4t..4t+3.
// R9 = R8 with the nontemporal builtins fixed (clang ext_vector_type instead
// of HIP_vector_type, which __builtin_nontemporal_* rejects):
//  - L2 prime: XCD swizzle gives XCD x two whole (b,h) pairs (K+V slice 2 MB
//    < 4 MB per-XCD L2). First 512 blocks/XCD issue one dense float4 prime
//    load per thread (full slice), saturating HBM up front so gather waves
//    hit warm L2 instead of latency-chained cold HBM.
//  - Non-temporal Q loads / O stores: single-use 16 MB streams don't evict
//    the primed K/V slice.

#define BB 2
#define LL 2048
#define HH 8
#define EE 64
#define SS 2048

typedef float floatx4 __attribute__((ext_vector_type(4)));

template<int CTRL>
__device__ __forceinline__ float dpp_add(float v) {
    int t = __builtin_amdgcn_mov_dpp(__float_as_int(v), CTRL, 0xF, 0xF, false);
    return v + __int_as_float(t);
}

__global__ __launch_bounds__(256) void logsparse_attn_kernel(
    const float* __restrict__ Q,
    const float* __restrict__ K,
    const float* __restrict__ V,
    float* __restrict__ O)
{
    const int lane = threadIdx.x & 63;
    const int wv   = threadIdx.x >> 6;
    // XCD-aware swizzle: launch block i -> XCD i%8; XCD x owns logical
    // range [x*1024,(x+1)*1024) = 2 whole (b,h) pairs.
    const int xcd = blockIdx.x & 7;
    const int q   = blockIdx.x >> 3;
    const int lb  = (xcd << 10) | q;
    const int row = lb * 4 + wv;            // consecutive waves -> consecutive l
    const int l  = row % LL;
    const int bh = row / LL;
    const int h  = bh & (HH - 1);
    const int b  = bh / HH;

    // ---- L2 prime: first 512 blocks per XCD stream the XCD's 2 MB K+V slice.
    // 131072 float4 units per XCD (2 pairs x 2048 s x 16 units x 2 tensors).
    float sink = 0.0f;
    {
        const int p = q * 256 + (int)threadIdx.x;   // 0..262143
        if (p < 131072) {                           // wave-uniform per block
            const int tensor = p >> 16;             // 0 = K, 1 = V
            const int r    = p & 65535;
            const int pair = r >> 15;
            const int u    = r & 32767;
            const int s    = u >> 4;
            const int part = u & 15;
            const int pbh  = xcd * 2 + pair;
            const size_t off = ((size_t)(pbh >> 3) * SS + s) * 512
                             + (size_t)(pbh & 7) * 64 + part * 4;
            const float4 pv = tensor ? *(const float4*)(V + off)
                                     : *(const float4*)(K + off);
            sink = pv.x + pv.y + pv.z + pv.w;       // keeps the loads live
        }
    }

    const int t = lane & 15;   // dims 4t..4t+3
    const int g = lane >> 4;   // key group 0..3

    const size_t qbase = (((size_t)b * LL + l) * HH + h) * (size_t)EE;
    const floatx4 qf = __builtin_nontemporal_load((const floatx4*)(Q + qbase + 4 * t));

    const size_t bhoff = (size_t)b * ((size_t)SS * HH * EE) + (size_t)h * EE;
    const float* Kb = K + bhoff;
    const float* Vb = V + bhoff;

    // wave-uniform active-key bookkeeping
    int ntaps, nkeys, w0;
    if (l < 22) { ntaps = 0; nkeys = l + 1; w0 = 0; }
    else {
        w0 = l - 10;
        ntaps = 32 - __clz(w0);            // floor(log2(w0)) + 1
        if (ntaps > 11) ntaps = 11;
        nkeys = ntaps + 11;                // taps + 11-wide window
    }

    float  sc[6];
    float4 vv[6];
    #pragma unroll
    for (int c = 0; c < 6; ++c) {
        const int n  = 4 * c + g;
        const int nc = (n < nkeys) ? n : (nkeys - 1);   // clamp for safe load
        int key;
        if (l < 22)           key = nc;
        else if (nc < ntaps)  key = w0 - (1 << (ntaps - 1 - nc));  // log taps
        else                  key = w0 + (nc - ntaps);             // window
        const size_t off = ((size_t)key << 9) + 4 * t;  // key*H*E = key*512
        const float4 kf = *(const float4*)(Kb + off);
        vv[c] = *(const float4*)(Vb + off);

        float p = qf.x * kf.x + qf.y * kf.y + qf.z * kf.z + qf.w * kf.w;
        p = dpp_add<0xB1>(p);    // quad_perm(1,0,3,2)  xor1
        p = dpp_add<0x4E>(p);    // quad_perm(2,3,0,1)  xor2
        p = dpp_add<0x124>(p);   // row_ror:4
        p = dpp_add<0x128>(p);   // row_ror:8 -> sum replicated in 16-lane group
        sc[c] = (n < nkeys) ? p * 0.125f : -1e30f;
    }

    // per-group max (group-uniform, register-only)
    float mg = sc[0];
    #pragma unroll
    for (int c = 1; c < 6; ++c) mg = fmaxf(mg, sc[c]);

    // independent exps + weighted V accumulate
    float  lsum = 0.0f;
    float4 acc  = {0.f, 0.f, 0.f, 0.f};
    #pragma unroll
    for (int c = 0; c < 6; ++c) {
        const float w = __expf(sc[c] - mg);   // invalid: exp(-1e30-mg)=0
        lsum  += w;
        acc.x += w * vv[c].x;
        acc.y += w * vv[c].y;
        acc.z += w * vv[c].z;
        acc.w += w * vv[c].w;
    }
    lsum += sink * 0.0f;   // exact no-op on finite data; keeps prime loads live

    // global max + rescale (fully-invalid group: exp(-1e30-M)=0 kills it)
    float M = mg;
    M = fmaxf(M, __shfl_xor(M, 16, 64));
    M = fmaxf(M, __shfl_xor(M, 32, 64));
    const float r = __expf(mg - M);
    lsum  *= r;
    acc.x *= r; acc.y *= r; acc.z *= r; acc.w *= r;

    // cross-group combine (plain sums after rescale)
    lsum  += __shfl_xor(lsum, 16, 64);    lsum  += __shfl_xor(lsum, 32, 64);
    acc.x += __shfl_xor(acc.x, 16, 64);   acc.x += __shfl_xor(acc.x, 32, 64);
    acc.y += __shfl_xor(acc.y, 16, 64);   acc.y += __shfl_xor(acc.y, 32, 64);
    acc.z += __shfl_xor(acc.z, 16, 64);   acc.z += __shfl_xor(acc.z, 32, 64);
    acc.w += __shfl_xor(acc.w, 16, 64);   acc.w += __shfl_xor(acc.w, 32, 64);

    if (g == 0) {
        const float inv = 1.0f / lsum;
        floatx4 o;
        o.x = acc.x * inv; o.y = acc.y * inv;
        o.z = acc.z * inv; o.w = acc.w * inv;
        __builtin_nontemporal_store(o, (floatx4*)(O + qbase + 4 * t));
    }
}

extern "C" void kernel_launch(void* const* d_in, const int* in_sizes, int n_in,
                              void* d_out, int out_size, void* d_ws, size_t ws_size,
                              hipStream_t stream) {
    const float* Q = (const float*)d_in[0];
    const float* K = (const float*)d_in[1];
    const float* V = (const float*)d_in[2];
    // d_in[3] = attention_mask (all-ones, unused by the reference math)
    float* O = (float*)d_out;

    const int rows   = BB * HH * LL;   // 32768 waves
    const int blocks = rows / 4;       // 8192 blocks, 4 waves each
    hipLaunchKernelGGL(logsparse_attn_kernel, dim3(blocks), dim3(256), 0, stream,
                       Q, K, V, O);
}

// Round 10
// 93.346 us; speedup vs baseline: 1.0448x; 1.0281x over previous
//
#include <hip/hip_runtime.h>

// LogSparseAttention: B=2, L=2048, H=8, E=D=64, S=2048. fp32 in/out.
// Mask row r (from reference _row_mask, L==S==2048, log_l=11):
//   r < 22 : keys 0..r (full causal prefix)
//   r >= 22: window {r-10..r} + taps {r-10-2^i, i=0..10, >= 0}
// <=22 active keys/row -> 6 chunks of 4 keys. Wave = one (b,h,l) row,
// 4 groups x 16 lanes; group g owns key ordinal 4c+g, lane (g,t) dims 4t..4t+3.
// R10 = exact R5 gather (best measured) + SEPARATE XCD-matched prime kernel:
// kernel boundary guarantees the prime completes before any gather load
// (R9's in-kernel prime had no ordering; R6's prep warmed the WRONG XCDs'
// L2s). Block i -> XCD i%8; XCD x primes its own gather slice (bh pairs
// {2x,2x+1}, 2 MB < 4 MB per-XCD L2) with dense float4 reads.

#define BB 2
#define LL 2048
#define HH 8
#define EE 64
#define SS 2048

template<int CTRL>
__device__ __forceinline__ float dpp_add(float v) {
    int t = __builtin_amdgcn_mov_dpp(__float_as_int(v), CTRL, 0xF, 0xF, false);
    return v + __int_as_float(t);
}

// ---- prime: XCD x streams K+V for bh pairs {2x,2x+1} into its L2 ----
// 1024 blocks x 256 threads x 4 float4 units = 1,048,576 units = 16 MB.
__global__ __launch_bounds__(256) void prime_kernel(
    const float* __restrict__ K,
    const float* __restrict__ V,
    float* __restrict__ sinkbuf)
{
    const int xcd = blockIdx.x & 7;
    const int li  = blockIdx.x >> 3;          // 0..127 within XCD
    float s4 = 0.0f;
    #pragma unroll
    for (int u = 0; u < 4; ++u) {
        const int unit  = li * 1024 + u * 256 + (int)threadIdx.x;  // 0..131071
        const int tensor = unit >> 16;        // 0 = K, 1 = V
        const int r     = unit & 65535;
        const int pair  = r >> 15;
        const int w     = r & 32767;
        const int s     = w >> 4;
        const int part  = w & 15;
        const int pbh   = xcd * 2 + pair;
        const size_t off = ((size_t)(pbh >> 3) * SS + s) * 512
                         + (size_t)(pbh & 7) * 64 + part * 4;
        const float4 pv = tensor ? *(const float4*)(V + off)
                                 : *(const float4*)(K + off);
        s4 += pv.x + pv.y + pv.z + pv.w;      // keep loads live
    }
    sinkbuf[blockIdx.x * 256 + threadIdx.x] = s4;   // 1 MB to d_ws
}

// ---- gather: exact R5 body ----
__global__ __launch_bounds__(256) void logsparse_attn_kernel(
    const float* __restrict__ Q,
    const float* __restrict__ K,
    const float* __restrict__ V,
    float* __restrict__ O)
{
    const int lane = threadIdx.x & 63;
    const int wv   = threadIdx.x >> 6;
    // XCD-aware swizzle: launch block i -> XCD i%8; XCD x owns logical
    // range [x*1024,(x+1)*1024) = 2 whole (b,h) pairs (matches prime).
    const int lb  = ((blockIdx.x & 7) << 10) | (blockIdx.x >> 3);
    const int row = lb * 4 + wv;            // consecutive waves -> consecutive l
    const int l  = row % LL;
    const int bh = row / LL;
    const int h  = bh & (HH - 1);
    const int b  = bh / HH;

    const int t = lane & 15;   // dims 4t..4t+3
    const int g = lane >> 4;   // key group 0..3

    const size_t qbase = (((size_t)b * LL + l) * HH + h) * (size_t)EE;
    const float4 qf = *(const float4*)(Q + qbase + 4 * t);

    const size_t bhoff = (size_t)b * ((size_t)SS * HH * EE) + (size_t)h * EE;
    const float* Kb = K + bhoff;
    const float* Vb = V + bhoff;

    // wave-uniform active-key bookkeeping
    int ntaps, nkeys, w0;
    if (l < 22) { ntaps = 0; nkeys = l + 1; w0 = 0; }
    else {
        w0 = l - 10;
        ntaps = 32 - __clz(w0);            // floor(log2(w0)) + 1
        if (ntaps > 11) ntaps = 11;
        nkeys = ntaps + 11;                // taps + 11-wide window
    }

    float  sc[6];
    float4 vv[6];
    #pragma unroll
    for (int c = 0; c < 6; ++c) {
        const int n  = 4 * c + g;
        const int nc = (n < nkeys) ? n : (nkeys - 1);   // clamp for safe load
        int key;
        if (l < 22)           key = nc;
        else if (nc < ntaps)  key = w0 - (1 << (ntaps - 1 - nc));  // log taps
        else                  key = w0 + (nc - ntaps);             // window
        const size_t off = ((size_t)key << 9) + 4 * t;  // key*H*E = key*512
        const float4 kf = *(const float4*)(Kb + off);
        vv[c] = *(const float4*)(Vb + off);

        float p = qf.x * kf.x + qf.y * kf.y + qf.z * kf.z + qf.w * kf.w;
        p = dpp_add<0xB1>(p);    // quad_perm(1,0,3,2)  xor1
        p = dpp_add<0x4E>(p);    // quad_perm(2,3,0,1)  xor2
        p = dpp_add<0x124>(p);   // row_ror:4
        p = dpp_add<0x128>(p);   // row_ror:8 -> sum replicated in 16-lane group
        sc[c] = (n < nkeys) ? p * 0.125f : -1e30f;
    }

    // per-group max (group-uniform, register-only)
    float mg = sc[0];
    #pragma unroll
    for (int c = 1; c < 6; ++c) mg = fmaxf(mg, sc[c]);

    // independent exps + weighted V accumulate
    float  lsum = 0.0f;
    float4 acc  = {0.f, 0.f, 0.f, 0.f};
    #pragma unroll
    for (int c = 0; c < 6; ++c) {
        const float w = __expf(sc[c] - mg);   // invalid: exp(-1e30-mg)=0
        lsum  += w;
        acc.x += w * vv[c].x;
        acc.y += w * vv[c].y;
        acc.z += w * vv[c].z;
        acc.w += w * vv[c].w;
    }

    // global max + rescale (fully-invalid group: exp(-1e30-M)=0 kills it)
    float M = mg;
    M = fmaxf(M, __shfl_xor(M, 16, 64));
    M = fmaxf(M, __shfl_xor(M, 32, 64));
    const float r = __expf(mg - M);
    lsum  *= r;
    acc.x *= r; acc.y *= r; acc.z *= r; acc.w *= r;

    // cross-group combine (plain sums after rescale)
    lsum  += __shfl_xor(lsum, 16, 64);    lsum  += __shfl_xor(lsum, 32, 64);
    acc.x += __shfl_xor(acc.x, 16, 64);   acc.x += __shfl_xor(acc.x, 32, 64);
    acc.y += __shfl_xor(acc.y, 16, 64);   acc.y += __shfl_xor(acc.y, 32, 64);
    acc.z += __shfl_xor(acc.z, 16, 64);   acc.z += __shfl_xor(acc.z, 32, 64);
    acc.w += __shfl_xor(acc.w, 16, 64);   acc.w += __shfl_xor(acc.w, 32, 64);

    if (g == 0) {
        const float inv = 1.0f / lsum;
        float4 o;
        o.x = acc.x * inv; o.y = acc.y * inv;
        o.z = acc.z * inv; o.w = acc.w * inv;
        *(float4*)(O + qbase + 4 * t) = o;
    }
}

extern "C" void kernel_launch(void* const* d_in, const int* in_sizes, int n_in,
                              void* d_out, int out_size, void* d_ws, size_t ws_size,
                              hipStream_t stream) {
    const float* Q = (const float*)d_in[0];
    const float* K = (const float*)d_in[1];
    const float* V = (const float*)d_in[2];
    // d_in[3] = attention_mask (all-ones, unused by the reference math)
    float* O = (float*)d_out;

    // 1) prime each XCD's L2 with its own K/V slice (ordered by stream)
    hipLaunchKernelGGL(prime_kernel, dim3(1024), dim3(256), 0, stream,
                       K, V, (float*)d_ws);
    // 2) gather (exact R5 body)
    const int rows   = BB * HH * LL;   // 32768 waves
    const int blocks = rows / 4;       // 8192 blocks, 4 waves each
    hipLaunchKernelGGL(logsparse_attn_kernel, dim3(blocks), dim3(256), 0, stream,
                       Q, K, V, O);
}